// Round 8
// baseline (120.776 us; speedup 1.0000x reference)
//
#include <hip/hip_runtime.h>

#define DIM 512

typedef unsigned int uint;
typedef unsigned short ushort;
typedef __attribute__((ext_vector_type(8))) short short8;
typedef __attribute__((ext_vector_type(4))) float f32x4;

// Pack two fp32 -> two bf16 (RNE-ish via +0x8000), lo16 = first arg.
__device__ __forceinline__ uint pack_bf16(float a, float b) {
    union { float f; uint u; } ua, ub;
    ua.f = a; ub.f = b;
    uint x0 = ua.u + 0x8000u;
    uint x1 = ub.u + 0x8000u;
    return __builtin_amdgcn_perm(x1, x0, 0x07060302);
}

// (bf16 pair u) * (x_even, x_odd) -> bf16 pair. lo16 of u = even element.
__device__ __forceinline__ uint mul_pack(uint u, float xl, float xh) {
    union { float f; uint u; } lo, hi, a, b;
    lo.u = u << 16;            // fp32 of even bf16
    hi.u = u & 0xffff0000u;    // fp32 of odd bf16
    a.f = lo.f * xl;
    b.f = hi.f * xh;
    return __builtin_amdgcn_perm(b.u + 0x8000u, a.u + 0x8000u, 0x07060302);
}

// =====================================================================
// K1: convert y and z (256x512 fp32) to bf16 in MFMA-fragment-swizzled
// order: elem (row,k) -> dst[(g*16+kt)*512 + lane*8 + j], g=row>>4,
// kt=k>>5, lane=((k>>3)&3)*16+(row&15), j=k&7. A wave's frag load for
// (g,kt) is ONE contiguous 1KB dwordx4 load.
// =====================================================================
__global__ void conv_swizzle(const float* __restrict__ z, const float* __restrict__ y,
                             ushort* __restrict__ zbf, ushort* __restrict__ ybf) {
    int t = blockIdx.x * 256 + threadIdx.x;      // 0..32767
    int idx = t & 16383;
    const float* src = (t < 16384) ? z : y;
    ushort* dst = (t < 16384) ? zbf : ybf;
    int r15  = idx & 15;
    int quad = (idx >> 4) & 3;
    int kt   = (idx >> 6) & 15;
    int g    = idx >> 10;
    const float* p = src + (g * 16 + r15) * DIM + kt * 32 + quad * 8;
    float4 a = *(const float4*)(p);
    float4 b = *(const float4*)(p + 4);
    uint4 o;
    o.x = pack_bf16(a.x, a.y);
    o.y = pack_bf16(a.z, a.w);
    o.z = pack_bf16(b.x, b.y);
    o.w = pack_bf16(b.z, b.w);
    *(uint4*)(dst + idx * 8) = o;
}

// =====================================================================
// K2: ONE WAVE PER BLOCK (64 thr), tile 32 rows x 64 cols of T[a,:,:].
// grid 8192 = a(256) x rt(8) x ct(4). No LDS, no barriers, fully
// independent waves; register double-buffered frag loads from the
// L2-resident swizzled ybf/zbf. 16 waves/CU -> statistical latency hiding.
// Partials: rowP[a][ct][r] (4 col-splits), colP[a][rt][s] (8 row-splits).
// =====================================================================
__global__ void __launch_bounds__(64, 4)
gemm_tile(const float* __restrict__ x,
          const ushort* __restrict__ ybf, const ushort* __restrict__ zbf,
          float* __restrict__ rowMp, float* __restrict__ rowSp,
          float* __restrict__ colMp, float* __restrict__ colSp,
          uint* __restrict__ counter) {
    const int bid = blockIdx.x;
    if (bid == 0 && threadIdx.x == 0) *counter = 0u;   // reset K3's flag

    const int a  = bid >> 5;
    const int rt = (bid >> 2) & 7;   // row strip of 32
    const int ct = bid & 3;          // col strip of 64
    const int lane = threadIdx.x;
    const int quad = lane >> 4;
    const int ln15 = lane & 15;

    const ushort* ybase = ybf + (rt * 2) * 8192 + lane * 8;   // + i*8192 + kt*512
    const ushort* zbase = zbf + (ct * 4) * 8192 + lane * 8;   // + j*8192 + kt*512
    const float*  xrow  = x + a * DIM + quad * 8;             // + kt*32

    f32x4 acc[2][4];
    #pragma unroll
    for (int i = 0; i < 2; ++i)
        #pragma unroll
        for (int j = 0; j < 4; ++j)
            acc[i][j] = (f32x4){0.f, 0.f, 0.f, 0.f};

    uint4 yu[2][2], zu[2][4];
    #pragma unroll
    for (int i = 0; i < 2; ++i) yu[0][i] = *(const uint4*)(ybase + i * 8192);
    #pragma unroll
    for (int j = 0; j < 4; ++j) zu[0][j] = *(const uint4*)(zbase + j * 8192);

    #pragma unroll 2
    for (int kt = 0; kt < 16; ++kt) {
        const int cur = kt & 1, nxt = cur ^ 1;
        if (kt < 15) {   // issue next tile's 6 frag loads first (one iter ahead)
            #pragma unroll
            for (int i = 0; i < 2; ++i)
                yu[nxt][i] = *(const uint4*)(ybase + i * 8192 + (kt + 1) * 512);
            #pragma unroll
            for (int j = 0; j < 4; ++j)
                zu[nxt][j] = *(const uint4*)(zbase + j * 8192 + (kt + 1) * 512);
        }
        float4 x0 = *(const float4*)(xrow + kt * 32);      // quad-broadcast, L1-hot
        float4 x1 = *(const float4*)(xrow + kt * 32 + 4);

        short8 af[2], bfr[4];
        #pragma unroll
        for (int i = 0; i < 2; ++i) {
            uint4 o;
            o.x = mul_pack(yu[cur][i].x, x0.x, x0.y);
            o.y = mul_pack(yu[cur][i].y, x0.z, x0.w);
            o.z = mul_pack(yu[cur][i].z, x1.x, x1.y);
            o.w = mul_pack(yu[cur][i].w, x1.z, x1.w);
            af[i] = *(short8*)&o;
        }
        #pragma unroll
        for (int j = 0; j < 4; ++j)
            bfr[j] = *(short8*)&zu[cur][j];
        #pragma unroll
        for (int i = 0; i < 2; ++i)
            #pragma unroll
            for (int j = 0; j < 4; ++j)
                acc[i][j] = __builtin_amdgcn_mfma_f32_16x16x32_bf16(af[i], bfr[j], acc[i][j], 0, 0, 0);
    }

    // ===== wave-local epilogue (no barriers) =====
    // lane owns rows r_loc = i*16 + quad*4 + reg, cols c_loc = j*16 + ln15
    // Row partials: max/sum over this tile's 64 cols.
    #pragma unroll
    for (int i = 0; i < 2; ++i) {
        #pragma unroll
        for (int reg = 0; reg < 4; ++reg) {
            float m = fmaxf(fmaxf(acc[i][0][reg], acc[i][1][reg]),
                            fmaxf(acc[i][2][reg], acc[i][3][reg]));
            #pragma unroll
            for (int d = 1; d < 16; d <<= 1) m = fmaxf(m, __shfl_xor(m, d, 64));
            float s = __expf(acc[i][0][reg] - m) + __expf(acc[i][1][reg] - m)
                    + __expf(acc[i][2][reg] - m) + __expf(acc[i][3][reg] - m);
            #pragma unroll
            for (int d = 1; d < 16; d <<= 1) s += __shfl_xor(s, d, 64);
            if (ln15 == 0) {
                int r = rt * 32 + i * 16 + quad * 4 + reg;
                rowMp[(a * 4 + ct) * 256 + r] = m;
                rowSp[(a * 4 + ct) * 256 + r] = s;
            }
        }
    }
    // Col partials: max/sum over this tile's 32 rows.
    #pragma unroll
    for (int j = 0; j < 4; ++j) {
        float m = -3.4e38f;
        #pragma unroll
        for (int i = 0; i < 2; ++i)
            #pragma unroll
            for (int reg = 0; reg < 4; ++reg)
                m = fmaxf(m, acc[i][j][reg]);
        m = fmaxf(m, __shfl_xor(m, 16, 64));
        m = fmaxf(m, __shfl_xor(m, 32, 64));
        float s = 0.f;
        #pragma unroll
        for (int i = 0; i < 2; ++i)
            #pragma unroll
            for (int reg = 0; reg < 4; ++reg)
                s += __expf(acc[i][j][reg] - m);
        s += __shfl_xor(s, 16, 64);
        s += __shfl_xor(s, 32, 64);
        if (quad == 0) {
            int sg = ct * 64 + j * 16 + ln15;
            colMp[(a * 8 + rt) * 256 + sg] = m;
            colSp[(a * 8 + rt) * 256 + sg] = s;
        }
    }
}

// ---- block-wide reductions over 256 threads ----
__device__ __forceinline__ float blk_max(float v, float* sm) {
    #pragma unroll
    for (int d = 1; d < 64; d <<= 1) v = fmaxf(v, __shfl_xor(v, d, 64));
    __syncthreads();
    if ((threadIdx.x & 63) == 0) sm[threadIdx.x >> 6] = v;
    __syncthreads();
    return fmaxf(fmaxf(sm[0], sm[1]), fmaxf(sm[2], sm[3]));
}
__device__ __forceinline__ float blk_sum(float v, float* sm) {
    #pragma unroll
    for (int d = 1; d < 64; d <<= 1) v += __shfl_xor(v, d, 64);
    __syncthreads();
    if ((threadIdx.x & 63) == 0) sm[threadIdx.x >> 6] = v;
    __syncthreads();
    return sm[0] + sm[1] + sm[2] + sm[3];
}

// =====================================================================
// K3: per-index LSE combine (4/8-way partial merge) + fused diag +
// last-block final reduction.
// =====================================================================
__global__ void combine_final(const float* __restrict__ rowMp, const float* __restrict__ rowSp,
                              const float* __restrict__ colMp, const float* __restrict__ colSp,
                              const float* __restrict__ x, const float* __restrict__ y,
                              const float* __restrict__ z,
                              float* __restrict__ m123, uint* __restrict__ counter,
                              float* __restrict__ out) {
    __shared__ float sm[4];
    __shared__ uint isLast;
    int b = blockIdx.x, t = threadIdx.x;

    // M1[b]: LSE over (ct, r) of rowP[b][ct][r]
    float lm = -3.4e38f, ls = 0.f;
    #pragma unroll
    for (int c = 0; c < 4; ++c) {
        float m = rowMp[(b * 4 + c) * 256 + t];
        float s = rowSp[(b * 4 + c) * 256 + t];
        float nm = fmaxf(lm, m);
        ls = ls * __expf(lm - nm) + s * __expf(m - nm);
        lm = nm;
    }
    float M = blk_max(lm, sm);
    float S = blk_sum(ls * __expf(lm - M), sm);
    float M1 = M + __logf(S);

    // M2[b]: LSE over (a=t, ct) of rowP[a][ct][b]
    lm = -3.4e38f; ls = 0.f;
    #pragma unroll
    for (int c = 0; c < 4; ++c) {
        float m = rowMp[(t * 4 + c) * 256 + b];
        float s = rowSp[(t * 4 + c) * 256 + b];
        float nm = fmaxf(lm, m);
        ls = ls * __expf(lm - nm) + s * __expf(m - nm);
        lm = nm;
    }
    M = blk_max(lm, sm);
    S = blk_sum(ls * __expf(lm - M), sm);
    float M2 = M + __logf(S);

    // M3[b]: LSE over (a=t, rt) of colP[a][rt][b]
    lm = -3.4e38f; ls = 0.f;
    #pragma unroll
    for (int r = 0; r < 8; ++r) {
        float m = colMp[(t * 8 + r) * 256 + b];
        float s = colSp[(t * 8 + r) * 256 + b];
        float nm = fmaxf(lm, m);
        ls = ls * __expf(lm - nm) + s * __expf(m - nm);
        lm = nm;
    }
    M = blk_max(lm, sm);
    S = blk_sum(ls * __expf(lm - M), sm);
    float M3 = M + __logf(S);

    // diag T[b,b,b] exact fp32: 512 elems, 2 per thread
    float d = x[b * DIM + t] * y[b * DIM + t] * z[b * DIM + t]
            + x[b * DIM + 256 + t] * y[b * DIM + 256 + t] * z[b * DIM + 256 + t];
    float D = blk_sum(d, sm);

    if (t == 0) {
        m123[b] = M1 + M2 + M3 - 3.0f * D;
        __threadfence();
        isLast = (atomicAdd(counter, 1u) == 255u) ? 1u : 0u;
    }
    __syncthreads();
    if (isLast) {
        __threadfence();
        const volatile float* vm = (const volatile float*)m123;
        float S1 = blk_sum(vm[t], sm);
        if (t == 0) out[0] = S1 / 768.0f;
    }
}

extern "C" void kernel_launch(void* const* d_in, const int* in_sizes, int n_in,
                              void* d_out, int out_size, void* d_ws, size_t ws_size,
                              hipStream_t stream) {
    const float* x = (const float*)d_in[0];
    const float* y = (const float*)d_in[1];
    const float* z = (const float*)d_in[2];
    char* w = (char*)d_ws;
    ushort* zbf  = (ushort*)(w);                 // 262144 B
    ushort* ybf  = (ushort*)(w + 262144);        // 262144 B
    float* rowMp = (float*)(w + 524288);         // 1 MB
    float* rowSp = (float*)(w + 1572864);        // 1 MB
    float* colMp = (float*)(w + 2621440);        // 2 MB
    float* colSp = (float*)(w + 4718592);        // 2 MB
    float* m123  = (float*)(w + 6815744);        // 1 KB
    uint*  counter = (uint*)(w + 6816768);       // 4 B
    float* out  = (float*)d_out;

    conv_swizzle<<<128, 256, 0, stream>>>(z, y, zbf, ybf);
    gemm_tile<<<8192, 64, 0, stream>>>(x, ybf, zbf, rowMp, rowSp, colMp, colSp, counter);
    combine_final<<<256, 256, 0, stream>>>(rowMp, rowSp, colMp, colSp, x, y, z, m123, counter, out);
}

// Round 9
// 108.824 us; speedup vs baseline: 1.1098x; 1.1098x over previous
//
#include <hip/hip_runtime.h>

#define DIM 512

typedef unsigned int uint;
typedef unsigned short ushort;
typedef __attribute__((ext_vector_type(8))) short short8;
typedef __attribute__((ext_vector_type(4))) float f32x4;

// Pack two fp32 -> two bf16 (RNE-ish via +0x8000), lo16 = first arg.
__device__ __forceinline__ uint pack_bf16(float a, float b) {
    union { float f; uint u; } ua, ub;
    ua.f = a; ub.f = b;
    uint x0 = ua.u + 0x8000u;
    uint x1 = ub.u + 0x8000u;
    return __builtin_amdgcn_perm(x1, x0, 0x07060302);
}

// (bf16 pair u) * (x_even, x_odd) -> bf16 pair. lo16 of u = even element.
__device__ __forceinline__ uint mul_pack(uint u, float xl, float xh) {
    union { float f; uint u; } lo, hi, a, b;
    lo.u = u << 16;            // fp32 of even bf16
    hi.u = u & 0xffff0000u;    // fp32 of odd bf16
    a.f = lo.f * xl;
    b.f = hi.f * xh;
    return __builtin_amdgcn_perm(b.u + 0x8000u, a.u + 0x8000u, 0x07060302);
}

// =====================================================================
// K1: convert y and z (256x512 fp32) to bf16 in MFMA-fragment-swizzled
// order: elem (row,k) -> dst[(g*16+kt)*512 + lane*8 + j], g=row>>4,
// kt=k>>5, lane=((k>>3)&3)*16+(row&15), j=k&7. A wave's frag load for
// (g,kt) is ONE contiguous 1KB dwordx4 load.
// =====================================================================
__global__ void conv_swizzle(const float* __restrict__ z, const float* __restrict__ y,
                             ushort* __restrict__ zbf, ushort* __restrict__ ybf) {
    int t = blockIdx.x * 256 + threadIdx.x;      // 0..32767
    int idx = t & 16383;
    const float* src = (t < 16384) ? z : y;
    ushort* dst = (t < 16384) ? zbf : ybf;
    int r15  = idx & 15;
    int quad = (idx >> 4) & 3;
    int kt   = (idx >> 6) & 15;
    int g    = idx >> 10;
    const float* p = src + (g * 16 + r15) * DIM + kt * 32 + quad * 8;
    float4 a = *(const float4*)(p);
    float4 b = *(const float4*)(p + 4);
    uint4 o;
    o.x = pack_bf16(a.x, a.y);
    o.y = pack_bf16(a.z, a.w);
    o.z = pack_bf16(b.x, b.y);
    o.w = pack_bf16(b.z, b.w);
    *(uint4*)(dst + idx * 8) = o;
}

// =====================================================================
// K2: ONE WAVE PER BLOCK (64 thr), tile 64 rows x 64 cols of T[a,:,:].
// grid 4096 = a(256) x rt(4) x ct(4). No LDS, no barriers. 16 MFMA per
// 8KB of frag loads (2x the arithmetic intensity of the 32x64 tile) --
// attacks the TA/L1 vector-memory port, the hypothesized limiter.
// Partials: rowP[a][ct in 4][r], colP[a][rt in 4][s].
// =====================================================================
__global__ void __launch_bounds__(64, 4)
gemm_tile(const float* __restrict__ x,
          const ushort* __restrict__ ybf, const ushort* __restrict__ zbf,
          float* __restrict__ rowMp, float* __restrict__ rowSp,
          float* __restrict__ colMp, float* __restrict__ colSp,
          uint* __restrict__ counter) {
    const int bid = blockIdx.x;
    if (bid == 0 && threadIdx.x == 0) *counter = 0u;   // reset K3's flag

    const int a  = bid >> 4;
    const int rt = (bid >> 2) & 3;   // row strip of 64
    const int ct = bid & 3;          // col strip of 64
    const int lane = threadIdx.x;
    const int quad = lane >> 4;
    const int ln15 = lane & 15;

    const ushort* ybase = ybf + (rt * 4) * 8192 + lane * 8;   // + i*8192 + kt*512
    const ushort* zbase = zbf + (ct * 4) * 8192 + lane * 8;   // + j*8192 + kt*512
    const float*  xrow  = x + a * DIM + quad * 8;             // + kt*32

    f32x4 acc[4][4];
    #pragma unroll
    for (int i = 0; i < 4; ++i)
        #pragma unroll
        for (int j = 0; j < 4; ++j)
            acc[i][j] = (f32x4){0.f, 0.f, 0.f, 0.f};

    for (int kt = 0; kt < 16; ++kt) {
        uint4 yu[4], zu[4];
        #pragma unroll
        for (int i = 0; i < 4; ++i)
            yu[i] = *(const uint4*)(ybase + i * 8192 + kt * 512);
        #pragma unroll
        for (int j = 0; j < 4; ++j)
            zu[j] = *(const uint4*)(zbase + j * 8192 + kt * 512);
        float4 x0 = *(const float4*)(xrow + kt * 32);      // quad-broadcast, L1-hot
        float4 x1 = *(const float4*)(xrow + kt * 32 + 4);

        short8 af[4], bfr[4];
        #pragma unroll
        for (int j = 0; j < 4; ++j)
            bfr[j] = *(short8*)&zu[j];
        #pragma unroll
        for (int i = 0; i < 4; ++i) {
            uint4 o;
            o.x = mul_pack(yu[i].x, x0.x, x0.y);
            o.y = mul_pack(yu[i].y, x0.z, x0.w);
            o.z = mul_pack(yu[i].z, x1.x, x1.y);
            o.w = mul_pack(yu[i].w, x1.z, x1.w);
            af[i] = *(short8*)&o;
        }
        #pragma unroll
        for (int i = 0; i < 4; ++i)
            #pragma unroll
            for (int j = 0; j < 4; ++j)
                acc[i][j] = __builtin_amdgcn_mfma_f32_16x16x32_bf16(af[i], bfr[j], acc[i][j], 0, 0, 0);
    }

    // ===== wave-local epilogue (no barriers) =====
    // lane owns rows r_loc = i*16 + quad*4 + reg, cols c_loc = j*16 + ln15
    // Row partials: max/sum over this tile's 64 cols.
    #pragma unroll
    for (int i = 0; i < 4; ++i) {
        #pragma unroll
        for (int reg = 0; reg < 4; ++reg) {
            float m = fmaxf(fmaxf(acc[i][0][reg], acc[i][1][reg]),
                            fmaxf(acc[i][2][reg], acc[i][3][reg]));
            #pragma unroll
            for (int d = 1; d < 16; d <<= 1) m = fmaxf(m, __shfl_xor(m, d, 64));
            float s = __expf(acc[i][0][reg] - m) + __expf(acc[i][1][reg] - m)
                    + __expf(acc[i][2][reg] - m) + __expf(acc[i][3][reg] - m);
            #pragma unroll
            for (int d = 1; d < 16; d <<= 1) s += __shfl_xor(s, d, 64);
            if (ln15 == 0) {
                int r = rt * 64 + i * 16 + quad * 4 + reg;
                rowMp[(a * 4 + ct) * 256 + r] = m;
                rowSp[(a * 4 + ct) * 256 + r] = s;
            }
        }
    }
    // Col partials: max/sum over this tile's 64 rows.
    #pragma unroll
    for (int j = 0; j < 4; ++j) {
        float m = -3.4e38f;
        #pragma unroll
        for (int i = 0; i < 4; ++i)
            #pragma unroll
            for (int reg = 0; reg < 4; ++reg)
                m = fmaxf(m, acc[i][j][reg]);
        m = fmaxf(m, __shfl_xor(m, 16, 64));
        m = fmaxf(m, __shfl_xor(m, 32, 64));
        float s = 0.f;
        #pragma unroll
        for (int i = 0; i < 4; ++i)
            #pragma unroll
            for (int reg = 0; reg < 4; ++reg)
                s += __expf(acc[i][j][reg] - m);
        s += __shfl_xor(s, 16, 64);
        s += __shfl_xor(s, 32, 64);
        if (quad == 0) {
            int sg = ct * 64 + j * 16 + ln15;
            colMp[(a * 4 + rt) * 256 + sg] = m;
            colSp[(a * 4 + rt) * 256 + sg] = s;
        }
    }
}

// ---- block-wide reductions over 256 threads ----
__device__ __forceinline__ float blk_max(float v, float* sm) {
    #pragma unroll
    for (int d = 1; d < 64; d <<= 1) v = fmaxf(v, __shfl_xor(v, d, 64));
    __syncthreads();
    if ((threadIdx.x & 63) == 0) sm[threadIdx.x >> 6] = v;
    __syncthreads();
    return fmaxf(fmaxf(sm[0], sm[1]), fmaxf(sm[2], sm[3]));
}
__device__ __forceinline__ float blk_sum(float v, float* sm) {
    #pragma unroll
    for (int d = 1; d < 64; d <<= 1) v += __shfl_xor(v, d, 64);
    __syncthreads();
    if ((threadIdx.x & 63) == 0) sm[threadIdx.x >> 6] = v;
    __syncthreads();
    return sm[0] + sm[1] + sm[2] + sm[3];
}

// =====================================================================
// K3: per-index LSE combine (4-way partial merges) + fused diag +
// last-block final reduction.
// =====================================================================
__global__ void combine_final(const float* __restrict__ rowMp, const float* __restrict__ rowSp,
                              const float* __restrict__ colMp, const float* __restrict__ colSp,
                              const float* __restrict__ x, const float* __restrict__ y,
                              const float* __restrict__ z,
                              float* __restrict__ m123, uint* __restrict__ counter,
                              float* __restrict__ out) {
    __shared__ float sm[4];
    __shared__ uint isLast;
    int b = blockIdx.x, t = threadIdx.x;

    // M1[b]: LSE over (ct, r) of rowP[b][ct][r]
    float lm = -3.4e38f, ls = 0.f;
    #pragma unroll
    for (int c = 0; c < 4; ++c) {
        float m = rowMp[(b * 4 + c) * 256 + t];
        float s = rowSp[(b * 4 + c) * 256 + t];
        float nm = fmaxf(lm, m);
        ls = ls * __expf(lm - nm) + s * __expf(m - nm);
        lm = nm;
    }
    float M = blk_max(lm, sm);
    float S = blk_sum(ls * __expf(lm - M), sm);
    float M1 = M + __logf(S);

    // M2[b]: LSE over (a=t, ct) of rowP[a][ct][b]
    lm = -3.4e38f; ls = 0.f;
    #pragma unroll
    for (int c = 0; c < 4; ++c) {
        float m = rowMp[(t * 4 + c) * 256 + b];
        float s = rowSp[(t * 4 + c) * 256 + b];
        float nm = fmaxf(lm, m);
        ls = ls * __expf(lm - nm) + s * __expf(m - nm);
        lm = nm;
    }
    M = blk_max(lm, sm);
    S = blk_sum(ls * __expf(lm - M), sm);
    float M2 = M + __logf(S);

    // M3[b]: LSE over (a=t, rt) of colP[a][rt][b]
    lm = -3.4e38f; ls = 0.f;
    #pragma unroll
    for (int r = 0; r < 4; ++r) {
        float m = colMp[(t * 4 + r) * 256 + b];
        float s = colSp[(t * 4 + r) * 256 + b];
        float nm = fmaxf(lm, m);
        ls = ls * __expf(lm - nm) + s * __expf(m - nm);
        lm = nm;
    }
    M = blk_max(lm, sm);
    S = blk_sum(ls * __expf(lm - M), sm);
    float M3 = M + __logf(S);

    // diag T[b,b,b] exact fp32: 512 elems, 2 per thread
    float d = x[b * DIM + t] * y[b * DIM + t] * z[b * DIM + t]
            + x[b * DIM + 256 + t] * y[b * DIM + 256 + t] * z[b * DIM + 256 + t];
    float D = blk_sum(d, sm);

    if (t == 0) {
        m123[b] = M1 + M2 + M3 - 3.0f * D;
        __threadfence();
        isLast = (atomicAdd(counter, 1u) == 255u) ? 1u : 0u;
    }
    __syncthreads();
    if (isLast) {
        __threadfence();
        const volatile float* vm = (const volatile float*)m123;
        float S1 = blk_sum(vm[t], sm);
        if (t == 0) out[0] = S1 / 768.0f;
    }
}

extern "C" void kernel_launch(void* const* d_in, const int* in_sizes, int n_in,
                              void* d_out, int out_size, void* d_ws, size_t ws_size,
                              hipStream_t stream) {
    const float* x = (const float*)d_in[0];
    const float* y = (const float*)d_in[1];
    const float* z = (const float*)d_in[2];
    char* w = (char*)d_ws;
    ushort* zbf  = (ushort*)(w);                 // 262144 B
    ushort* ybf  = (ushort*)(w + 262144);        // 262144 B
    float* rowMp = (float*)(w + 524288);         // 1 MB
    float* rowSp = (float*)(w + 1572864);        // 1 MB
    float* colMp = (float*)(w + 2621440);        // 1 MB
    float* colSp = (float*)(w + 3670016);        // 1 MB
    float* m123  = (float*)(w + 4718592);        // 1 KB
    uint*  counter = (uint*)(w + 4719616);       // 4 B
    float* out  = (float*)d_out;

    conv_swizzle<<<128, 256, 0, stream>>>(z, y, zbf, ybf);
    gemm_tile<<<4096, 64, 0, stream>>>(x, ybf, zbf, rowMp, rowSp, colMp, colSp, counter);
    combine_final<<<256, 256, 0, stream>>>(rowMp, rowSp, colMp, colSp, x, y, z, m123, counter, out);
}